// Round 9
// baseline (255.837 us; speedup 1.0000x reference)
//
#include <hip/hip_runtime.h>

#define NROWS 65536
#define KDIM  512
constexpr float BN_EPS = 1e-5f;

using short8 = __attribute__((ext_vector_type(8))) short;
using f32x4  = __attribute__((ext_vector_type(4))) float;

#define BM 128

// RNE fp32 -> bf16 pack of 8 floats
__device__ __forceinline__ short8 cvthi8(const float4& a, const float4& b) {
  const float e[8] = {a.x, a.y, a.z, a.w, b.x, b.y, b.z, b.w};
  short8 h;
  #pragma unroll
  for (int i = 0; i < 8; ++i) {
    unsigned u = __float_as_uint(e[i]);
    u += 0x7FFFu + ((u >> 16) & 1u);
    h[i] = (short)(u >> 16);
  }
  return h;
}

// ---------------- prep: C1 -> fragment-tiled bf16 (RNE) ----------------
// entry e = kg*512 + col holds C1[kg*8 + i][col], i=0..7 (one B-fragment).
__global__ __launch_bounds__(256)
void prep_c1(const float* __restrict__ C1, short8* __restrict__ c1tH) {
  const int e   = blockIdx.x * 256 + threadIdx.x;   // 0..32767
  const int col = e & 511;
  const int kg  = e >> 9;
  short8 hi;
  #pragma unroll
  for (int i = 0; i < 8; ++i) {
    const float x = C1[(size_t)(kg * 8 + i) * KDIM + col];   // coalesced
    unsigned u = __float_as_uint(x);
    u += 0x7FFFu + ((u >> 16) & 1u);
    hi[i] = (short)(u >> 16);
  }
  c1tH[e] = hi;
}

// ---------------- quad: register-resident A (32 rows/wave), rf=2 B-reuse ----------------
// quad[n] = x_n^T C1 x_n (1-pass bf16 MFMA), fused column stats.
// Each of 4 waves owns 32 rows; A (32 x 512 bf16 = 128 VGPR) is loaded from
// HBM once. Main loop reads only B fragments from pre-tiled L2-resident c1t;
// each B fragment feeds TWO MFMAs (rf=2), and all 4 waves read the identical
// B stream at the same (jt,kt) -> L1 broadcast sharing. No LDS / no barriers
// in the main loop.
__global__ __launch_bounds__(256)
void quad_kernel(const float* __restrict__ X, const short8* __restrict__ c1tH,
                 float* __restrict__ quad,
                 float* __restrict__ colS1, float* __restrict__ colS2,
                 float* __restrict__ colS3, double* __restrict__ qsums) {
  __shared__ float qLds[BM];

  const int tid  = threadIdx.x;
  const int lane = tid & 63;
  const int w    = tid >> 6;          // wave 0..3 -> rows w*32..w*32+31
  const int g    = lane >> 4;         // k-group 0..3
  const int lr   = lane & 15;
  const int r0   = blockIdx.x * BM;

  // ---- one-time A load: lane (g,lr), rf half: X[r0+w*32+rf*16+lr][kt*32+g*8..+7] ----
  short8 A0[16], A1[16];
  {
    const float* xp0 = X + (size_t)(r0 + w * 32 + lr) * KDIM + g * 8;
    const float* xp1 = xp0 + 16 * KDIM;
    #pragma unroll
    for (int kt = 0; kt < 16; ++kt) {
      const float4 a0 = *(const float4*)(xp0 + kt * 32);
      const float4 a1 = *(const float4*)(xp0 + kt * 32 + 4);
      A0[kt] = cvthi8(a0, a1);
      const float4 b0 = *(const float4*)(xp1 + kt * 32);
      const float4 b1 = *(const float4*)(xp1 + kt * 32 + 4);
      A1[kt] = cvthi8(b0, b1);
    }
  }

  float qacc0[4] = {}, qacc1[4] = {};   // row partials (rows g*4+p of each rf half)

  for (int jt = 0; jt < 8; ++jt) {    // 8 j-tiles of 64 cols
    const int j0 = jt * 64;
    f32x4 acc0[4], acc1[4];
    #pragma unroll
    for (int cf = 0; cf < 4; ++cf) {
      acc0[cf] = (f32x4){0.f, 0.f, 0.f, 0.f};
      acc1[cf] = (f32x4){0.f, 0.f, 0.f, 0.f};
    }

    #pragma unroll
    for (int kt = 0; kt < 16; ++kt) {
      const int eb = (kt * 4 + g) * KDIM + j0 + lr;
      short8 b0 = c1tH[eb];
      short8 b1 = c1tH[eb + 16];
      short8 b2 = c1tH[eb + 32];
      short8 b3 = c1tH[eb + 48];
      acc0[0] = __builtin_amdgcn_mfma_f32_16x16x32_bf16(A0[kt], b0, acc0[0], 0, 0, 0);
      acc1[0] = __builtin_amdgcn_mfma_f32_16x16x32_bf16(A1[kt], b0, acc1[0], 0, 0, 0);
      acc0[1] = __builtin_amdgcn_mfma_f32_16x16x32_bf16(A0[kt], b1, acc0[1], 0, 0, 0);
      acc1[1] = __builtin_amdgcn_mfma_f32_16x16x32_bf16(A1[kt], b1, acc1[1], 0, 0, 0);
      acc0[2] = __builtin_amdgcn_mfma_f32_16x16x32_bf16(A0[kt], b2, acc0[2], 0, 0, 0);
      acc1[2] = __builtin_amdgcn_mfma_f32_16x16x32_bf16(A1[kt], b2, acc1[2], 0, 0, 0);
      acc0[3] = __builtin_amdgcn_mfma_f32_16x16x32_bf16(A0[kt], b3, acc0[3], 0, 0, 0);
      acc1[3] = __builtin_amdgcn_mfma_f32_16x16x32_bf16(A1[kt], b3, acc1[3], 0, 0, 0);
    }
    // epilogue: qacc[p] += Y[row, j] * X[row, j] over this j-tile
    #pragma unroll
    for (int p = 0; p < 4; ++p) {
      const float* xr0 = X + (size_t)(r0 + w * 32 + g * 4 + p) * KDIM + j0;
      const float* xr1 = xr0 + 16 * KDIM;
      float s0 = 0.f, s1 = 0.f;
      #pragma unroll
      for (int cf = 0; cf < 4; ++cf) {
        s0 += acc0[cf][p] * xr0[cf * 16 + lr];
        s1 += acc1[cf][p] * xr1[cf * 16 + lr];
      }
      qacc0[p] += s0;
      qacc1[p] += s1;
    }
  }

  // reduce across the 16 lr lanes of each k-group; one writer per row
  #pragma unroll
  for (int p = 0; p < 4; ++p) {
    float q0 = qacc0[p], q1 = qacc1[p];
    #pragma unroll
    for (int m = 1; m < 16; m <<= 1) {
      q0 += __shfl_xor(q0, m, 64);
      q1 += __shfl_xor(q1, m, 64);
    }
    if (lr == 0) {
      const int row0 = w * 32 + g * 4 + p;
      qLds[row0] = q0;
      quad[r0 + row0] = q0;
      qLds[row0 + 16] = q1;
      quad[r0 + row0 + 16] = q1;
    }
  }
  __syncthreads();
  // fused column stats over the (cache-hot) X panel
  {
    float s1a = 0.f, s2a = 0.f, s3a = 0.f, s1b = 0.f, s2b = 0.f, s3b = 0.f;
    for (int r = 0; r < BM; ++r) {
      const float q = qLds[r];
      const float* xp = X + (size_t)(r0 + r) * KDIM + tid;
      const float x0 = xp[0];
      const float x1 = xp[256];
      s1a += x0; s2a += x0 * x0; s3a += q * x0;
      s1b += x1; s2b += x1 * x1; s3b += q * x1;
    }
    atomicAdd(&colS1[tid], s1a); atomicAdd(&colS1[tid + 256], s1b);
    atomicAdd(&colS2[tid], s2a); atomicAdd(&colS2[tid + 256], s2b);
    atomicAdd(&colS3[tid], s3a); atomicAdd(&colS3[tid + 256], s3b);
  }
  if (tid < BM) {   // two waves: each reduces 64 lanes of q, q^2
    double q = (double)qLds[tid];
    double q2 = q * q;
    #pragma unroll
    for (int m = 1; m < 64; m <<= 1) {
      q  += __shfl_xor(q,  m, 64);
      q2 += __shfl_xor(q2, m, 64);
    }
    if ((tid & 63) == 0) { atomicAdd(&qsums[0], q); atomicAdd(&qsums[1], q2); }
  }
}

// ---------------- finalize per-feature mean / inv_std ----------------
__global__ void finalize_kernel(const float* __restrict__ colS1, const float* __restrict__ colS2,
                                const float* __restrict__ colS3, const double* __restrict__ qsums,
                                const float* __restrict__ C2, const float* __restrict__ C3,
                                float* __restrict__ mean, float* __restrict__ inv_std) {
  const int k = blockIdx.x * blockDim.x + threadIdx.x;
  if (k >= KDIM) return;
  const double invN = 1.0 / (double)NROWS;
  const double meanQ = qsums[0] * invN;
  const double varQ  = qsums[1] * invN - meanQ * meanQ;
  const float meanX = colS1[k] * (float)invN;
  const float varX  = colS2[k] * (float)invN - meanX * meanX;
  const float covQX = colS3[k] * (float)invN - (float)meanQ * meanX;
  const float c2 = C2[k];
  const float c3 = C3[0];
  const float m = (float)meanQ + c2 * meanX + c3;
  const float v = (float)varQ + c2 * c2 * varX + 2.0f * c2 * covQX;
  mean[k] = m;
  inv_std[k] = 1.0f / sqrtf(v + BN_EPS);
}

// ---------------- normalize + write ----------------
__global__ __launch_bounds__(256)
void normalize_kernel(const float* __restrict__ X, const float* __restrict__ quad,
                      const float* __restrict__ C2, const float* __restrict__ C3,
                      const float* __restrict__ mean, const float* __restrict__ inv_std,
                      float* __restrict__ out) {
  const int idx = blockIdx.x * blockDim.x + threadIdx.x;  // float4 index
  const int n = idx >> 7;
  const int j4 = idx & 127;
  const float q = quad[n];
  const float c3 = C3[0];
  const float4 x  = *(const float4*)&X[(size_t)idx * 4];
  const float4 c2 = *(const float4*)&C2[j4 * 4];
  const float4 m  = *(const float4*)&mean[j4 * 4];
  const float4 iv = *(const float4*)&inv_std[j4 * 4];
  float4 o;
  o.x = (q + c2.x * x.x + c3 - m.x) * iv.x;
  o.y = (q + c2.y * x.y + c3 - m.y) * iv.y;
  o.z = (q + c2.z * x.z + c3 - m.z) * iv.z;
  o.w = (q + c2.w * x.w + c3 - m.w) * iv.w;
  *(float4*)&out[(size_t)idx * 4] = o;
}

extern "C" void kernel_launch(void* const* d_in, const int* in_sizes, int n_in,
                              void* d_out, int out_size, void* d_ws, size_t ws_size,
                              hipStream_t stream) {
  const float* X  = (const float*)d_in[0];
  const float* C1 = (const float*)d_in[1];
  const float* C2 = (const float*)d_in[2];
  const float* C3 = (const float*)d_in[3];
  float* out = (float*)d_out;

  char* ws = (char*)d_ws;
  float*  quad    = (float*)ws;                                        // 256 KB
  float*  colS1   = (float*)(ws + (size_t)NROWS * 4);                  // K
  float*  colS2   = colS1 + KDIM;
  float*  colS3   = colS2 + KDIM;
  double* qsums   = (double*)(ws + (size_t)NROWS * 4 + 3 * KDIM * 4);  // 2 doubles
  float*  mean    = (float*)(ws + (size_t)NROWS * 4 + 3 * KDIM * 4 + 16);
  float*  inv_std = mean + KDIM;
  short8* c1tH    = (short8*)(ws + 276480);                            // 512 KB (16B aligned)

  hipMemsetAsync(colS1, 0, 3 * KDIM * 4 + 16, stream);

  prep_c1<<<128, 256, 0, stream>>>(C1, c1tH);
  quad_kernel<<<NROWS / BM, 256, 0, stream>>>(X, c1tH, quad,
                                              colS1, colS2, colS3, qsums);
  finalize_kernel<<<2, 256, 0, stream>>>(colS1, colS2, colS3, qsums, C2, C3, mean, inv_std);
  normalize_kernel<<<(NROWS * (KDIM / 4)) / 256, 256, 0, stream>>>(
      X, quad, C2, C3, mean, inv_std, out);
}

// Round 10
// 218.016 us; speedup vs baseline: 1.1735x; 1.1735x over previous
//
#include <hip/hip_runtime.h>

#define NROWS 65536
#define KDIM  512
constexpr float BN_EPS = 1e-5f;

using short8 = __attribute__((ext_vector_type(8))) short;
using f32x4  = __attribute__((ext_vector_type(4))) float;

#define BM 64

// async global->LDS, 16B per lane
__device__ __forceinline__ void gload_lds16(const float* g, float* l) {
  __builtin_amdgcn_global_load_lds(
      (const __attribute__((address_space(1))) void*)g,
      (__attribute__((address_space(3))) void*)l, 16, 0, 0);
}

// RNE fp32 -> bf16 pack of 8 floats
__device__ __forceinline__ short8 cvthi8(const float4& a, const float4& b) {
  const float e[8] = {a.x, a.y, a.z, a.w, b.x, b.y, b.z, b.w};
  short8 h;
  #pragma unroll
  for (int i = 0; i < 8; ++i) {
    unsigned u = __float_as_uint(e[i]);
    u += 0x7FFFu + ((u >> 16) & 1u);
    h[i] = (short)(u >> 16);
  }
  return h;
}

// ---------------- prep: C1 -> fragment-tiled bf16 (RNE) ----------------
// entry e = kg*512 + col holds C1[kg*8 + i][col], i=0..7 (one B-fragment).
// For a k-tile kt, entries kt*2048 .. kt*2048+2047 are one contiguous 32 KB
// block = exactly the B data the whole workgroup needs for that kt.
__global__ __launch_bounds__(256)
void prep_c1(const float* __restrict__ C1, short8* __restrict__ c1tH) {
  const int e   = blockIdx.x * 256 + threadIdx.x;   // 0..32767
  const int col = e & 511;
  const int kg  = e >> 9;
  short8 hi;
  #pragma unroll
  for (int i = 0; i < 8; ++i) {
    const float x = C1[(size_t)(kg * 8 + i) * KDIM + col];   // coalesced
    unsigned u = __float_as_uint(x);
    u += 0x7FFFu + ((u >> 16) & 1u);
    hi[i] = (short)(u >> 16);
  }
  c1tH[e] = hi;
}

// ---------------- quad: register-resident A + async-LDS-staged B ----------------
// quad[n] = x_n^T C1 x_n (1-pass bf16 MFMA), fused column stats.
// 8 waves: wave (wr,wc) owns rows wr*32..+31 x cols wc*128..+127.
// A (32x512 bf16 = 128 VGPR) loaded from HBM once, in-register.
// B: per kt, the 32 KB fragment-ordered slice of c1t is DMA'd into LDS
// (global_load_lds, double-buffered, issued BEFORE the compute phase so the
// end-of-kt __syncthreads drain is short). ds_read_b128 fragment reads are
// 256B-contiguous per 16-lane group -> conflict-free.
__global__ __launch_bounds__(512, 2)
void quad_kernel(const float* __restrict__ X, const short8* __restrict__ c1tH,
                 float* __restrict__ quad,
                 float* __restrict__ colS1, float* __restrict__ colS2,
                 float* __restrict__ colS3, double* __restrict__ qsums) {
  __shared__ short8 Bs[2][2048];      // 2 x 32 KB
  __shared__ float qPart[4][BM];
  __shared__ float qLds[BM];

  const int tid  = threadIdx.x;
  const int lane = tid & 63;
  const int w    = tid >> 6;          // wave 0..7
  const int wr   = w >> 2;            // row-half (0..1): rows wr*32..+31
  const int wc   = w & 3;             // col-quarter (0..3): cols wc*128..+127
  const int g    = lane >> 4;         // k-group 0..3
  const int lr   = lane & 15;
  const int r0   = blockIdx.x * BM;

#define STAGE(buf, kt)                                                     \
  {                                                                        \
    _Pragma("unroll")                                                      \
    for (int s = 0; s < 4; ++s)                                            \
      gload_lds16((const float*)(c1tH + (kt) * 2048 + s * 512 + tid),      \
                  (float*)&Bs[buf][s * 512 + tid]);                        \
  }

  // ---- B stage prologue (kt = 0) ----
  STAGE(0, 0);

  // ---- one-time A load: lane (g,lr), rf: X[r0+wr*32+rf*16+lr][kt*32+g*8..+7] ----
  short8 A[2][16];
  #pragma unroll
  for (int rf = 0; rf < 2; ++rf) {
    const float* xp = X + (size_t)(r0 + wr * 32 + rf * 16 + lr) * KDIM + g * 8;
    #pragma unroll
    for (int kt = 0; kt < 16; ++kt) {
      const float4 a0 = *(const float4*)(xp + kt * 32);
      const float4 a1 = *(const float4*)(xp + kt * 32 + 4);
      A[rf][kt] = cvthi8(a0, a1);
    }
  }

  f32x4 acc[2][8];
  #pragma unroll
  for (int rf = 0; rf < 2; ++rf)
    #pragma unroll
    for (int cf = 0; cf < 8; ++cf)
      acc[rf][cf] = (f32x4){0.f, 0.f, 0.f, 0.f};

  __syncthreads();                    // kt=0 stage complete

  int cur = 0;
  #pragma unroll
  for (int kt = 0; kt < 16; ++kt) {
    if (kt < 15) STAGE(cur ^ 1, kt + 1);   // async prefetch next kt
    const int fb = g * 512 + wc * 128 + lr;
    {
      const short8 b0 = Bs[cur][fb];
      const short8 b1 = Bs[cur][fb + 16];
      const short8 b2 = Bs[cur][fb + 32];
      const short8 b3 = Bs[cur][fb + 48];
      acc[0][0] = __builtin_amdgcn_mfma_f32_16x16x32_bf16(A[0][kt], b0, acc[0][0], 0, 0, 0);
      acc[1][0] = __builtin_amdgcn_mfma_f32_16x16x32_bf16(A[1][kt], b0, acc[1][0], 0, 0, 0);
      acc[0][1] = __builtin_amdgcn_mfma_f32_16x16x32_bf16(A[0][kt], b1, acc[0][1], 0, 0, 0);
      acc[1][1] = __builtin_amdgcn_mfma_f32_16x16x32_bf16(A[1][kt], b1, acc[1][1], 0, 0, 0);
      acc[0][2] = __builtin_amdgcn_mfma_f32_16x16x32_bf16(A[0][kt], b2, acc[0][2], 0, 0, 0);
      acc[1][2] = __builtin_amdgcn_mfma_f32_16x16x32_bf16(A[1][kt], b2, acc[1][2], 0, 0, 0);
      acc[0][3] = __builtin_amdgcn_mfma_f32_16x16x32_bf16(A[0][kt], b3, acc[0][3], 0, 0, 0);
      acc[1][3] = __builtin_amdgcn_mfma_f32_16x16x32_bf16(A[1][kt], b3, acc[1][3], 0, 0, 0);
    }
    {
      const short8 b4 = Bs[cur][fb + 64];
      const short8 b5 = Bs[cur][fb + 80];
      const short8 b6 = Bs[cur][fb + 96];
      const short8 b7 = Bs[cur][fb + 112];
      acc[0][4] = __builtin_amdgcn_mfma_f32_16x16x32_bf16(A[0][kt], b4, acc[0][4], 0, 0, 0);
      acc[1][4] = __builtin_amdgcn_mfma_f32_16x16x32_bf16(A[1][kt], b4, acc[1][4], 0, 0, 0);
      acc[0][5] = __builtin_amdgcn_mfma_f32_16x16x32_bf16(A[0][kt], b5, acc[0][5], 0, 0, 0);
      acc[1][5] = __builtin_amdgcn_mfma_f32_16x16x32_bf16(A[1][kt], b5, acc[1][5], 0, 0, 0);
      acc[0][6] = __builtin_amdgcn_mfma_f32_16x16x32_bf16(A[0][kt], b6, acc[0][6], 0, 0, 0);
      acc[1][6] = __builtin_amdgcn_mfma_f32_16x16x32_bf16(A[1][kt], b6, acc[1][6], 0, 0, 0);
      acc[0][7] = __builtin_amdgcn_mfma_f32_16x16x32_bf16(A[0][kt], b7, acc[0][7], 0, 0, 0);
      acc[1][7] = __builtin_amdgcn_mfma_f32_16x16x32_bf16(A[1][kt], b7, acc[1][7], 0, 0, 0);
    }
    __syncthreads();                  // drains the prefetch DMA; releases buf cur
    cur ^= 1;
  }
#undef STAGE

  // ---- epilogue: row-dot against X for this wave's 128-col slice ----
  #pragma unroll
  for (int rf = 0; rf < 2; ++rf)
    #pragma unroll
    for (int p = 0; p < 4; ++p) {
      const int row = wr * 32 + rf * 16 + g * 4 + p;
      const float* xr = X + (size_t)(r0 + row) * KDIM + wc * 128;
      float s = 0.f;
      #pragma unroll
      for (int cf = 0; cf < 8; ++cf)
        s += acc[rf][cf][p] * xr[cf * 16 + lr];
      s += __shfl_xor(s, 1, 64);
      s += __shfl_xor(s, 2, 64);
      s += __shfl_xor(s, 4, 64);
      s += __shfl_xor(s, 8, 64);
      if (lr == 0) qPart[wc][row] = s;
    }
  __syncthreads();
  if (tid < BM) {
    const float q = qPart[0][tid] + qPart[1][tid] + qPart[2][tid] + qPart[3][tid];
    quad[r0 + tid] = q;
    qLds[tid] = q;
  }
  __syncthreads();
  // ---- fused column stats over the (cache-hot) X panel: 1 col per thread ----
  {
    float s1 = 0.f, s2 = 0.f, s3 = 0.f;
    for (int r = 0; r < BM; ++r) {
      const float q = qLds[r];
      const float x = X[(size_t)(r0 + r) * KDIM + tid];
      s1 += x; s2 += x * x; s3 += q * x;
    }
    atomicAdd(&colS1[tid], s1);
    atomicAdd(&colS2[tid], s2);
    atomicAdd(&colS3[tid], s3);
  }
  if (tid < BM) {   // one full wave: reduce q, q^2 across 64 lanes
    double q = (double)qLds[tid];
    double q2 = q * q;
    #pragma unroll
    for (int m = 1; m < 64; m <<= 1) {
      q  += __shfl_xor(q,  m, 64);
      q2 += __shfl_xor(q2, m, 64);
    }
    if (tid == 0) { atomicAdd(&qsums[0], q); atomicAdd(&qsums[1], q2); }
  }
}

// ---------------- finalize per-feature mean / inv_std ----------------
__global__ void finalize_kernel(const float* __restrict__ colS1, const float* __restrict__ colS2,
                                const float* __restrict__ colS3, const double* __restrict__ qsums,
                                const float* __restrict__ C2, const float* __restrict__ C3,
                                float* __restrict__ mean, float* __restrict__ inv_std) {
  const int k = blockIdx.x * blockDim.x + threadIdx.x;
  if (k >= KDIM) return;
  const double invN = 1.0 / (double)NROWS;
  const double meanQ = qsums[0] * invN;
  const double varQ  = qsums[1] * invN - meanQ * meanQ;
  const float meanX = colS1[k] * (float)invN;
  const float varX  = colS2[k] * (float)invN - meanX * meanX;
  const float covQX = colS3[k] * (float)invN - (float)meanQ * meanX;
  const float c2 = C2[k];
  const float c3 = C3[0];
  const float m = (float)meanQ + c2 * meanX + c3;
  const float v = (float)varQ + c2 * c2 * varX + 2.0f * c2 * covQX;
  mean[k] = m;
  inv_std[k] = 1.0f / sqrtf(v + BN_EPS);
}

// ---------------- normalize + write ----------------
__global__ __launch_bounds__(256)
void normalize_kernel(const float* __restrict__ X, const float* __restrict__ quad,
                      const float* __restrict__ C2, const float* __restrict__ C3,
                      const float* __restrict__ mean, const float* __restrict__ inv_std,
                      float* __restrict__ out) {
  const int idx = blockIdx.x * blockDim.x + threadIdx.x;  // float4 index
  const int n = idx >> 7;
  const int j4 = idx & 127;
  const float q = quad[n];
  const float c3 = C3[0];
  const float4 x  = *(const float4*)&X[(size_t)idx * 4];
  const float4 c2 = *(const float4*)&C2[j4 * 4];
  const float4 m  = *(const float4*)&mean[j4 * 4];
  const float4 iv = *(const float4*)&inv_std[j4 * 4];
  float4 o;
  o.x = (q + c2.x * x.x + c3 - m.x) * iv.x;
  o.y = (q + c2.y * x.y + c3 - m.y) * iv.y;
  o.z = (q + c2.z * x.z + c3 - m.z) * iv.z;
  o.w = (q + c2.w * x.w + c3 - m.w) * iv.w;
  *(float4*)&out[(size_t)idx * 4] = o;
}

extern "C" void kernel_launch(void* const* d_in, const int* in_sizes, int n_in,
                              void* d_out, int out_size, void* d_ws, size_t ws_size,
                              hipStream_t stream) {
  const float* X  = (const float*)d_in[0];
  const float* C1 = (const float*)d_in[1];
  const float* C2 = (const float*)d_in[2];
  const float* C3 = (const float*)d_in[3];
  float* out = (float*)d_out;

  char* ws = (char*)d_ws;
  float*  quad    = (float*)ws;                                        // 256 KB
  float*  colS1   = (float*)(ws + (size_t)NROWS * 4);                  // K
  float*  colS2   = colS1 + KDIM;
  float*  colS3   = colS2 + KDIM;
  double* qsums   = (double*)(ws + (size_t)NROWS * 4 + 3 * KDIM * 4);  // 2 doubles
  float*  mean    = (float*)(ws + (size_t)NROWS * 4 + 3 * KDIM * 4 + 16);
  float*  inv_std = mean + KDIM;
  short8* c1tH    = (short8*)(ws + 276480);                            // 512 KB (16B aligned)

  hipMemsetAsync(colS1, 0, 3 * KDIM * 4 + 16, stream);

  prep_c1<<<128, 256, 0, stream>>>(C1, c1tH);
  quad_kernel<<<NROWS / BM, 512, 0, stream>>>(X, c1tH, quad,
                                              colS1, colS2, colS3, qsums);
  finalize_kernel<<<2, 256, 0, stream>>>(colS1, colS2, colS3, qsums, C2, C3, mean, inv_std);
  normalize_kernel<<<(NROWS * (KDIM / 4)) / 256, 256, 0, stream>>>(
      X, quad, C2, C3, mean, inv_std, out);
}

// Round 11
// 179.371 us; speedup vs baseline: 1.4263x; 1.2154x over previous
//
#include <hip/hip_runtime.h>

#define NROWS 65536
#define KDIM  512
constexpr float BN_EPS = 1e-5f;

using short8 = __attribute__((ext_vector_type(8))) short;
using f32x4  = __attribute__((ext_vector_type(4))) float;

#define BM 64

// RNE fp32 -> bf16 pack of 8 floats
__device__ __forceinline__ short8 cvthi8(const float4& a, const float4& b) {
  const float e[8] = {a.x, a.y, a.z, a.w, b.x, b.y, b.z, b.w};
  short8 h;
  #pragma unroll
  for (int i = 0; i < 8; ++i) {
    unsigned u = __float_as_uint(e[i]);
    u += 0x7FFFu + ((u >> 16) & 1u);
    h[i] = (short)(u >> 16);
  }
  return h;
}

// ---------------- prep: C1 -> fragment-tiled bf16 (RNE) ----------------
// entry e = kg*512 + col holds C1[kg*8 + i][col], i=0..7 (one B-fragment).
__global__ __launch_bounds__(256)
void prep_c1(const float* __restrict__ C1, short8* __restrict__ c1tH) {
  const int e   = blockIdx.x * 256 + threadIdx.x;   // 0..32767
  const int col = e & 511;
  const int kg  = e >> 9;
  short8 hi;
  #pragma unroll
  for (int i = 0; i < 8; ++i) {
    const float x = C1[(size_t)(kg * 8 + i) * KDIM + col];   // coalesced
    unsigned u = __float_as_uint(x);
    u += 0x7FFFu + ((u >> 16) & 1u);
    hi[i] = (short)(u >> 16);
  }
  c1tH[e] = hi;
}

// ---------------- quad: 32 rows x 128 cols per wave, zero-barrier, direct feeds ----------------
// quad[n] = x_n^T C1 x_n (1-pass bf16 MFMA), fused column stats.
// 8 waves = 2 row-groups x 4 col-groups; BM=64 rows/block; single kt loop
// (cols are wave-split, so there is NO jt loop and A is read exactly once
// per col-wave). B fragments come straight from the pre-tiled L2-resident
// c1t; 32 rows/wave halves B bytes/FLOP vs the 16-row variant (TA-bound).
// No LDS, no __syncthreads, no launch-bounds occupancy cap in the main loop.
__global__ __launch_bounds__(512)
void quad_kernel(const float* __restrict__ X, const short8* __restrict__ c1tH,
                 float* __restrict__ quad,
                 float* __restrict__ colS1, float* __restrict__ colS2,
                 float* __restrict__ colS3, double* __restrict__ qsums) {
  __shared__ float qPart[4][BM];
  __shared__ float qLds[BM];

  const int tid  = threadIdx.x;
  const int lane = tid & 63;
  const int w    = tid >> 6;          // wave 0..7
  const int wr   = w >> 2;            // row-group (0..1): rows wr*32..+31
  const int wc   = w & 3;             // col-group (0..3): cols wc*128..+127
  const int g    = lane >> 4;         // k-group 0..3
  const int lr   = lane & 15;
  const int r0   = blockIdx.x * BM;

  f32x4 acc[2][8];
  #pragma unroll
  for (int rf = 0; rf < 2; ++rf)
    #pragma unroll
    for (int cf = 0; cf < 8; ++cf)
      acc[rf][cf] = (f32x4){0.f, 0.f, 0.f, 0.f};

  // A stream bases: lane (g,lr) reads rows wr*32+rf*16+lr, k = kt*32+g*8..+7
  const float* xpA0 = X + (size_t)(r0 + wr * 32 + lr) * KDIM + g * 8;
  const float* xpA1 = xpA0 + 16 * KDIM;
  // B base: fragments for cols wc*128+cf*16+lr at k-group (kt*4+g)
  const short8* bbase = c1tH + g * 512 + wc * 128 + lr;

  #pragma unroll
  for (int kt = 0; kt < 16; ++kt) {
    // A: 4 x 16B loads (imm-offset addressing), cvt to bf16 in-register
    const float4 a00 = *(const float4*)(xpA0 + kt * 32);
    const float4 a01 = *(const float4*)(xpA0 + kt * 32 + 4);
    const float4 a10 = *(const float4*)(xpA1 + kt * 32);
    const float4 a11 = *(const float4*)(xpA1 + kt * 32 + 4);
    const short8 A0 = cvthi8(a00, a01);
    const short8 A1 = cvthi8(a10, a11);
    // B: 8 x 16B independent loads from L2-resident pre-tiled c1t
    const short8* bp = bbase + kt * 2048;
    const short8 b0 = bp[0],   b1 = bp[16],  b2 = bp[32],  b3 = bp[48];
    const short8 b4 = bp[64],  b5 = bp[80],  b6 = bp[96],  b7 = bp[112];
    acc[0][0] = __builtin_amdgcn_mfma_f32_16x16x32_bf16(A0, b0, acc[0][0], 0, 0, 0);
    acc[1][0] = __builtin_amdgcn_mfma_f32_16x16x32_bf16(A1, b0, acc[1][0], 0, 0, 0);
    acc[0][1] = __builtin_amdgcn_mfma_f32_16x16x32_bf16(A0, b1, acc[0][1], 0, 0, 0);
    acc[1][1] = __builtin_amdgcn_mfma_f32_16x16x32_bf16(A1, b1, acc[1][1], 0, 0, 0);
    acc[0][2] = __builtin_amdgcn_mfma_f32_16x16x32_bf16(A0, b2, acc[0][2], 0, 0, 0);
    acc[1][2] = __builtin_amdgcn_mfma_f32_16x16x32_bf16(A1, b2, acc[1][2], 0, 0, 0);
    acc[0][3] = __builtin_amdgcn_mfma_f32_16x16x32_bf16(A0, b3, acc[0][3], 0, 0, 0);
    acc[1][3] = __builtin_amdgcn_mfma_f32_16x16x32_bf16(A1, b3, acc[1][3], 0, 0, 0);
    acc[0][4] = __builtin_amdgcn_mfma_f32_16x16x32_bf16(A0, b4, acc[0][4], 0, 0, 0);
    acc[1][4] = __builtin_amdgcn_mfma_f32_16x16x32_bf16(A1, b4, acc[1][4], 0, 0, 0);
    acc[0][5] = __builtin_amdgcn_mfma_f32_16x16x32_bf16(A0, b5, acc[0][5], 0, 0, 0);
    acc[1][5] = __builtin_amdgcn_mfma_f32_16x16x32_bf16(A1, b5, acc[1][5], 0, 0, 0);
    acc[0][6] = __builtin_amdgcn_mfma_f32_16x16x32_bf16(A0, b6, acc[0][6], 0, 0, 0);
    acc[1][6] = __builtin_amdgcn_mfma_f32_16x16x32_bf16(A1, b6, acc[1][6], 0, 0, 0);
    acc[0][7] = __builtin_amdgcn_mfma_f32_16x16x32_bf16(A0, b7, acc[0][7], 0, 0, 0);
    acc[1][7] = __builtin_amdgcn_mfma_f32_16x16x32_bf16(A1, b7, acc[1][7], 0, 0, 0);
  }

  // ---- epilogue: row-dot against X for this wave's 128-col slice ----
  #pragma unroll
  for (int rf = 0; rf < 2; ++rf)
    #pragma unroll
    for (int p = 0; p < 4; ++p) {
      const int row = wr * 32 + rf * 16 + g * 4 + p;
      const float* xr = X + (size_t)(r0 + row) * KDIM + wc * 128;
      float s = 0.f;
      #pragma unroll
      for (int cf = 0; cf < 8; ++cf)
        s += acc[rf][cf][p] * xr[cf * 16 + lr];
      s += __shfl_xor(s, 1, 64);
      s += __shfl_xor(s, 2, 64);
      s += __shfl_xor(s, 4, 64);
      s += __shfl_xor(s, 8, 64);
      if (lr == 0) qPart[wc][row] = s;
    }
  __syncthreads();
  if (tid < BM) {
    const float q = qPart[0][tid] + qPart[1][tid] + qPart[2][tid] + qPart[3][tid];
    quad[r0 + tid] = q;
    qLds[tid] = q;
  }
  __syncthreads();
  // ---- fused column stats over the (cache-hot) X panel: 1 col per thread ----
  {
    float s1 = 0.f, s2 = 0.f, s3 = 0.f;
    for (int r = 0; r < BM; ++r) {
      const float q = qLds[r];
      const float x = X[(size_t)(r0 + r) * KDIM + tid];
      s1 += x; s2 += x * x; s3 += q * x;
    }
    atomicAdd(&colS1[tid], s1);
    atomicAdd(&colS2[tid], s2);
    atomicAdd(&colS3[tid], s3);
  }
  if (tid < BM) {   // one full wave: reduce q, q^2 across 64 lanes
    double q = (double)qLds[tid];
    double q2 = q * q;
    #pragma unroll
    for (int m = 1; m < 64; m <<= 1) {
      q  += __shfl_xor(q,  m, 64);
      q2 += __shfl_xor(q2, m, 64);
    }
    if (tid == 0) { atomicAdd(&qsums[0], q); atomicAdd(&qsums[1], q2); }
  }
}

// ---------------- finalize per-feature mean / inv_std ----------------
__global__ void finalize_kernel(const float* __restrict__ colS1, const float* __restrict__ colS2,
                                const float* __restrict__ colS3, const double* __restrict__ qsums,
                                const float* __restrict__ C2, const float* __restrict__ C3,
                                float* __restrict__ mean, float* __restrict__ inv_std) {
  const int k = blockIdx.x * blockDim.x + threadIdx.x;
  if (k >= KDIM) return;
  const double invN = 1.0 / (double)NROWS;
  const double meanQ = qsums[0] * invN;
  const double varQ  = qsums[1] * invN - meanQ * meanQ;
  const float meanX = colS1[k] * (float)invN;
  const float varX  = colS2[k] * (float)invN - meanX * meanX;
  const float covQX = colS3[k] * (float)invN - (float)meanQ * meanX;
  const float c2 = C2[k];
  const float c3 = C3[0];
  const float m = (float)meanQ + c2 * meanX + c3;
  const float v = (float)varQ + c2 * c2 * varX + 2.0f * c2 * covQX;
  mean[k] = m;
  inv_std[k] = 1.0f / sqrtf(v + BN_EPS);
}

// ---------------- normalize + write ----------------
__global__ __launch_bounds__(256)
void normalize_kernel(const float* __restrict__ X, const float* __restrict__ quad,
                      const float* __restrict__ C2, const float* __restrict__ C3,
                      const float* __restrict__ mean, const float* __restrict__ inv_std,
                      float* __restrict__ out) {
  const int idx = blockIdx.x * blockDim.x + threadIdx.x;  // float4 index
  const int n = idx >> 7;
  const int j4 = idx & 127;
  const float q = quad[n];
  const float c3 = C3[0];
  const float4 x  = *(const float4*)&X[(size_t)idx * 4];
  const float4 c2 = *(const float4*)&C2[j4 * 4];
  const float4 m  = *(const float4*)&mean[j4 * 4];
  const float4 iv = *(const float4*)&inv_std[j4 * 4];
  float4 o;
  o.x = (q + c2.x * x.x + c3 - m.x) * iv.x;
  o.y = (q + c2.y * x.y + c3 - m.y) * iv.y;
  o.z = (q + c2.z * x.z + c3 - m.z) * iv.z;
  o.w = (q + c2.w * x.w + c3 - m.w) * iv.w;
  *(float4*)&out[(size_t)idx * 4] = o;
}

extern "C" void kernel_launch(void* const* d_in, const int* in_sizes, int n_in,
                              void* d_out, int out_size, void* d_ws, size_t ws_size,
                              hipStream_t stream) {
  const float* X  = (const float*)d_in[0];
  const float* C1 = (const float*)d_in[1];
  const float* C2 = (const float*)d_in[2];
  const float* C3 = (const float*)d_in[3];
  float* out = (float*)d_out;

  char* ws = (char*)d_ws;
  float*  quad    = (float*)ws;                                        // 256 KB
  float*  colS1   = (float*)(ws + (size_t)NROWS * 4);                  // K
  float*  colS2   = colS1 + KDIM;
  float*  colS3   = colS2 + KDIM;
  double* qsums   = (double*)(ws + (size_t)NROWS * 4 + 3 * KDIM * 4);  // 2 doubles
  float*  mean    = (float*)(ws + (size_t)NROWS * 4 + 3 * KDIM * 4 + 16);
  float*  inv_std = mean + KDIM;
  short8* c1tH    = (short8*)(ws + 276480);                            // 512 KB (16B aligned)

  hipMemsetAsync(colS1, 0, 3 * KDIM * 4 + 16, stream);

  prep_c1<<<128, 256, 0, stream>>>(C1, c1tH);
  quad_kernel<<<NROWS / BM, 512, 0, stream>>>(X, c1tH, quad,
                                              colS1, colS2, colS3, qsums);
  finalize_kernel<<<2, 256, 0, stream>>>(colS1, colS2, colS3, qsums, C2, C3, mean, inv_std);
  normalize_kernel<<<(NROWS * (KDIM / 4)) / 256, 256, 0, stream>>>(
      X, quad, C2, C3, mean, inv_std, out);
}

// Round 12
// 170.223 us; speedup vs baseline: 1.5029x; 1.0537x over previous
//
#include <hip/hip_runtime.h>

#define NROWS 65536
#define KDIM  512
constexpr float BN_EPS = 1e-5f;

using short8 = __attribute__((ext_vector_type(8))) short;
using f32x4  = __attribute__((ext_vector_type(4))) float;

#define BM 64

// async global->LDS, 16B per lane
__device__ __forceinline__ void gload_lds16(const float* g, float* l) {
  __builtin_amdgcn_global_load_lds(
      (const __attribute__((address_space(1))) void*)g,
      (__attribute__((address_space(3))) void*)l, 16, 0, 0);
}

// RNE fp32 -> bf16 pack of 8 floats
__device__ __forceinline__ short8 cvthi8(const float4& a, const float4& b) {
  const float e[8] = {a.x, a.y, a.z, a.w, b.x, b.y, b.z, b.w};
  short8 h;
  #pragma unroll
  for (int i = 0; i < 8; ++i) {
    unsigned u = __float_as_uint(e[i]);
    u += 0x7FFFu + ((u >> 16) & 1u);
    h[i] = (short)(u >> 16);
  }
  return h;
}

// ---------------- prep: C1 -> fragment-tiled bf16 (RNE) ----------------
// entry e = kg*512 + col holds C1[kg*8 + i][col], i=0..7 (one B-fragment).
// k-tile kt's 32 KB block (entries kt*2048..+2047) is exactly what a
// workgroup needs for that kt, in linear order -> pure DMA staging.
__global__ __launch_bounds__(256)
void prep_c1(const float* __restrict__ C1, short8* __restrict__ c1tH) {
  const int e   = blockIdx.x * 256 + threadIdx.x;   // 0..32767
  const int col = e & 511;
  const int kg  = e >> 9;
  short8 hi;
  #pragma unroll
  for (int i = 0; i < 8; ++i) {
    const float x = C1[(size_t)(kg * 8 + i) * KDIM + col];   // coalesced
    unsigned u = __float_as_uint(x);
    u += 0x7FFFu + ((u >> 16) & 1u);
    hi[i] = (short)(u >> 16);
  }
  c1tH[e] = hi;
}

// ---------------- quad: streamed A + async-LDS-staged B (2-phase) ----------------
// quad[n] = x_n^T C1 x_n (1-pass bf16 MFMA), fused column stats.
// 8 waves = 2 row-groups x 4 col-groups (wave tile 32 rows x 128 cols).
// B: per kt, 32 KB DMA'd into LDS via global_load_lds (double-buffered,
// issued BEFORE the compute phase so the end-of-kt barrier drain is
// covered by MFMA + ds_read time). B never touches VGPRs in flight ->
// the wave's registers are free for the 4 A-landing slots + acc (AGPR).
// A streamed per kt (imm-offset addressing), cvt in-register.
__global__ __launch_bounds__(512)
void quad_kernel(const float* __restrict__ X, const short8* __restrict__ c1tH,
                 float* __restrict__ quad,
                 float* __restrict__ colS1, float* __restrict__ colS2,
                 float* __restrict__ colS3, double* __restrict__ qsums) {
  __shared__ short8 Bs[2][2048];      // 2 x 32 KB
  __shared__ float qPart[4][BM];
  __shared__ float qLds[BM];

  const int tid  = threadIdx.x;
  const int lane = tid & 63;
  const int w    = tid >> 6;          // wave 0..7
  const int wr   = w >> 2;            // row-group (0..1): rows wr*32..+31
  const int wc   = w & 3;             // col-group (0..3): cols wc*128..+127
  const int g    = lane >> 4;         // k-group 0..3
  const int lr   = lane & 15;
  const int r0   = blockIdx.x * BM;

#define STAGE(buf, kt)                                                     \
  {                                                                        \
    _Pragma("unroll")                                                      \
    for (int s = 0; s < 4; ++s)                                            \
      gload_lds16((const float*)(c1tH + (kt) * 2048 + s * 512 + tid),      \
                  (float*)&Bs[buf][s * 512 + tid]);                        \
  }

  // A stream bases: lane (g,lr) reads rows wr*32+rf*16+lr, k = kt*32+g*8..+7
  const float* xpA0 = X + (size_t)(r0 + wr * 32 + lr) * KDIM + g * 8;
  const float* xpA1 = xpA0 + 16 * KDIM;

  f32x4 acc[2][8];
  #pragma unroll
  for (int rf = 0; rf < 2; ++rf)
    #pragma unroll
    for (int cf = 0; cf < 8; ++cf)
      acc[rf][cf] = (f32x4){0.f, 0.f, 0.f, 0.f};

  STAGE(0, 0);                        // prologue stage kt=0
  __syncthreads();

  int cur = 0;
  #pragma unroll
  for (int kt = 0; kt < 16; ++kt) {
    if (kt < 15) STAGE(cur ^ 1, kt + 1);   // async prefetch next kt (no VGPRs)

    // A: 4 x 16B loads, cvt to bf16 in-register
    const float4 a00 = *(const float4*)(xpA0 + kt * 32);
    const float4 a01 = *(const float4*)(xpA0 + kt * 32 + 4);
    const float4 a10 = *(const float4*)(xpA1 + kt * 32);
    const float4 a11 = *(const float4*)(xpA1 + kt * 32 + 4);
    const short8 A0 = cvthi8(a00, a01);
    const short8 A1 = cvthi8(a10, a11);

    // B fragments from LDS (256B-contiguous per 16-lane group, conflict-free)
    const int fb = g * 512 + wc * 128 + lr;
    {
      const short8 b0 = Bs[cur][fb];
      const short8 b1 = Bs[cur][fb + 16];
      const short8 b2 = Bs[cur][fb + 32];
      const short8 b3 = Bs[cur][fb + 48];
      acc[0][0] = __builtin_amdgcn_mfma_f32_16x16x32_bf16(A0, b0, acc[0][0], 0, 0, 0);
      acc[1][0] = __builtin_amdgcn_mfma_f32_16x16x32_bf16(A1, b0, acc[1][0], 0, 0, 0);
      acc[0][1] = __builtin_amdgcn_mfma_f32_16x16x32_bf16(A0, b1, acc[0][1], 0, 0, 0);
      acc[1][1] = __builtin_amdgcn_mfma_f32_16x16x32_bf16(A1, b1, acc[1][1], 0, 0, 0);
      acc[0][2] = __builtin_amdgcn_mfma_f32_16x16x32_bf16(A0, b2, acc[0][2], 0, 0, 0);
      acc[1][2] = __builtin_amdgcn_mfma_f32_16x16x32_bf16(A1, b2, acc[1][2], 0, 0, 0);
      acc[0][3] = __builtin_amdgcn_mfma_f32_16x16x32_bf16(A0, b3, acc[0][3], 0, 0, 0);
      acc[1][3] = __builtin_amdgcn_mfma_f32_16x16x32_bf16(A1, b3, acc[1][3], 0, 0, 0);
    }
    {
      const short8 b4 = Bs[cur][fb + 64];
      const short8 b5 = Bs[cur][fb + 80];
      const short8 b6 = Bs[cur][fb + 96];
      const short8 b7 = Bs[cur][fb + 112];
      acc[0][4] = __builtin_amdgcn_mfma_f32_16x16x32_bf16(A0, b4, acc[0][4], 0, 0, 0);
      acc[1][4] = __builtin_amdgcn_mfma_f32_16x16x32_bf16(A1, b4, acc[1][4], 0, 0, 0);
      acc[0][5] = __builtin_amdgcn_mfma_f32_16x16x32_bf16(A0, b5, acc[0][5], 0, 0, 0);
      acc[1][5] = __builtin_amdgcn_mfma_f32_16x16x32_bf16(A1, b5, acc[1][5], 0, 0, 0);
      acc[0][6] = __builtin_amdgcn_mfma_f32_16x16x32_bf16(A0, b6, acc[0][6], 0, 0, 0);
      acc[1][6] = __builtin_amdgcn_mfma_f32_16x16x32_bf16(A1, b6, acc[1][6], 0, 0, 0);
      acc[0][7] = __builtin_amdgcn_mfma_f32_16x16x32_bf16(A0, b7, acc[0][7], 0, 0, 0);
      acc[1][7] = __builtin_amdgcn_mfma_f32_16x16x32_bf16(A1, b7, acc[1][7], 0, 0, 0);
    }
    __syncthreads();                  // release buf cur; prefetch has landed
    cur ^= 1;
  }
#undef STAGE

  // ---- epilogue: row-dot against X for this wave's 128-col slice ----
  #pragma unroll
  for (int rf = 0; rf < 2; ++rf)
    #pragma unroll
    for (int p = 0; p < 4; ++p) {
      const int row = wr * 32 + rf * 16 + g * 4 + p;
      const float* xr = X + (size_t)(r0 + row) * KDIM + wc * 128;
      float s = 0.f;
      #pragma unroll
      for (int cf = 0; cf < 8; ++cf)
        s += acc[rf][cf][p] * xr[cf * 16 + lr];
      s += __shfl_xor(s, 1, 64);
      s += __shfl_xor(s, 2, 64);
      s += __shfl_xor(s, 4, 64);
      s += __shfl_xor(s, 8, 64);
      if (lr == 0) qPart[wc][row] = s;
    }
  __syncthreads();
  if (tid < BM) {
    const float q = qPart[0][tid] + qPart[1][tid] + qPart[2][tid] + qPart[3][tid];
    quad[r0 + tid] = q;
    qLds[tid] = q;
  }
  __syncthreads();
  // ---- fused column stats over the (cache-hot) X panel: 1 col per thread ----
  {
    float s1 = 0.f, s2 = 0.f, s3 = 0.f;
    for (int r = 0; r < BM; ++r) {
      const float q = qLds[r];
      const float x = X[(size_t)(r0 + r) * KDIM + tid];
      s1 += x; s2 += x * x; s3 += q * x;
    }
    atomicAdd(&colS1[tid], s1);
    atomicAdd(&colS2[tid], s2);
    atomicAdd(&colS3[tid], s3);
  }
  if (tid < BM) {   // one full wave: reduce q, q^2 across 64 lanes
    double q = (double)qLds[tid];
    double q2 = q * q;
    #pragma unroll
    for (int m = 1; m < 64; m <<= 1) {
      q  += __shfl_xor(q,  m, 64);
      q2 += __shfl_xor(q2, m, 64);
    }
    if (tid == 0) { atomicAdd(&qsums[0], q); atomicAdd(&qsums[1], q2); }
  }
}

// ---------------- finalize per-feature mean / inv_std ----------------
__global__ void finalize_kernel(const float* __restrict__ colS1, const float* __restrict__ colS2,
                                const float* __restrict__ colS3, const double* __restrict__ qsums,
                                const float* __restrict__ C2, const float* __restrict__ C3,
                                float* __restrict__ mean, float* __restrict__ inv_std) {
  const int k = blockIdx.x * blockDim.x + threadIdx.x;
  if (k >= KDIM) return;
  const double invN = 1.0 / (double)NROWS;
  const double meanQ = qsums[0] * invN;
  const double varQ  = qsums[1] * invN - meanQ * meanQ;
  const float meanX = colS1[k] * (float)invN;
  const float varX  = colS2[k] * (float)invN - meanX * meanX;
  const float covQX = colS3[k] * (float)invN - (float)meanQ * meanX;
  const float c2 = C2[k];
  const float c3 = C3[0];
  const float m = (float)meanQ + c2 * meanX + c3;
  const float v = (float)varQ + c2 * c2 * varX + 2.0f * c2 * covQX;
  mean[k] = m;
  inv_std[k] = 1.0f / sqrtf(v + BN_EPS);
}

// ---------------- normalize + write ----------------
__global__ __launch_bounds__(256)
void normalize_kernel(const float* __restrict__ X, const float* __restrict__ quad,
                      const float* __restrict__ C2, const float* __restrict__ C3,
                      const float* __restrict__ mean, const float* __restrict__ inv_std,
                      float* __restrict__ out) {
  const int idx = blockIdx.x * blockDim.x + threadIdx.x;  // float4 index
  const int n = idx >> 7;
  const int j4 = idx & 127;
  const float q = quad[n];
  const float c3 = C3[0];
  const float4 x  = *(const float4*)&X[(size_t)idx * 4];
  const float4 c2 = *(const float4*)&C2[j4 * 4];
  const float4 m  = *(const float4*)&mean[j4 * 4];
  const float4 iv = *(const float4*)&inv_std[j4 * 4];
  float4 o;
  o.x = (q + c2.x * x.x + c3 - m.x) * iv.x;
  o.y = (q + c2.y * x.y + c3 - m.y) * iv.y;
  o.z = (q + c2.z * x.z + c3 - m.z) * iv.z;
  o.w = (q + c2.w * x.w + c3 - m.w) * iv.w;
  *(float4*)&out[(size_t)idx * 4] = o;
}

extern "C" void kernel_launch(void* const* d_in, const int* in_sizes, int n_in,
                              void* d_out, int out_size, void* d_ws, size_t ws_size,
                              hipStream_t stream) {
  const float* X  = (const float*)d_in[0];
  const float* C1 = (const float*)d_in[1];
  const float* C2 = (const float*)d_in[2];
  const float* C3 = (const float*)d_in[3];
  float* out = (float*)d_out;

  char* ws = (char*)d_ws;
  float*  quad    = (float*)ws;                                        // 256 KB
  float*  colS1   = (float*)(ws + (size_t)NROWS * 4);                  // K
  float*  colS2   = colS1 + KDIM;
  float*  colS3   = colS2 + KDIM;
  double* qsums   = (double*)(ws + (size_t)NROWS * 4 + 3 * KDIM * 4);  // 2 doubles
  float*  mean    = (float*)(ws + (size_t)NROWS * 4 + 3 * KDIM * 4 + 16);
  float*  inv_std = mean + KDIM;
  short8* c1tH    = (short8*)(ws + 276480);                            // 512 KB (16B aligned)

  hipMemsetAsync(colS1, 0, 3 * KDIM * 4 + 16, stream);

  prep_c1<<<128, 256, 0, stream>>>(C1, c1tH);
  quad_kernel<<<NROWS / BM, 512, 0, stream>>>(X, c1tH, quad,
                                              colS1, colS2, colS3, qsums);
  finalize_kernel<<<2, 256, 0, stream>>>(colS1, colS2, colS3, qsums, C2, C3, mean, inv_std);
  normalize_kernel<<<(NROWS * (KDIM / 4)) / 256, 256, 0, stream>>>(
      X, quad, C2, C3, mean, inv_std, out);
}